// Round 5
// baseline (109.778 us; speedup 1.0000x reference)
//
#include <hip/hip_runtime.h>

// labels[b,l,c] = argmin_q ( LN(t)[b,l,c] - LN(code_book)[c,q] )
//              = argmax_q LN(code_book)[c,q]        (tn constant along q)
//              = argmax_q code_book[c,q]            (global-scalar LN is monotone)
// => output is a 256-entry per-c label vector broadcast over (B, L).
//
// v5: coalesced scan. v1's per-thread-row scan made every wave-load a
// 64-distinct-cache-line gather (lanes stride 1024 B). Here each wave
// processes one row per iteration: lane l loads cols 4l..4l+3 (the 64
// lanes cover the full 1 KB row contiguously -> 16 lines/instr, 4x fewer
// line requests), then a 6-step shfl_xor butterfly reduces argmax.
// The butterfly op is "max by (value desc, index asc)" — a total order,
// associative & commutative, so the reduction is exact and reproduces
// jnp.argmin's first-index tie-breaking.

#define C_DIM 256
#define Q_DIM 256
#define OUT_INT4 (4 * 512 * 256 / 4)   // B*L*C / 4 = 131072 int4 stores
#define NBLOCKS 128

__global__ __launch_bounds__(256) void rpq_fused(const float* __restrict__ cb,
                                                 int* __restrict__ out) {
    __shared__ int s[C_DIM];
    const int tid  = threadIdx.x;
    const int lane = tid & 63;
    const int wave = tid >> 6;

    // Wave w owns rows [64w, 64w+64). One coalesced row-load per iteration.
#pragma unroll 4
    for (int k = 0; k < 64; ++k) {
        const int row = wave * 64 + k;
        float4 v = *(const float4*)(cb + row * Q_DIM + lane * 4);
        // In-lane merge of 4 candidates, ascending index with strict '>'
        // keeps the earliest index on ties.
        float b  = v.x;
        int  idx = lane * 4;
        if (v.y > b) { b = v.y; idx = lane * 4 + 1; }
        if (v.z > b) { b = v.z; idx = lane * 4 + 2; }
        if (v.w > b) { b = v.w; idx = lane * 4 + 3; }
        // Butterfly argmax across 64 lanes: take the partner's candidate iff
        // it has a larger value, or equal value and smaller index.
#pragma unroll
        for (int off = 1; off < 64; off <<= 1) {
            float ob = __shfl_xor(b, off, 64);
            int   oi = __shfl_xor(idx, off, 64);
            if (ob > b || (ob == b && oi < idx)) { b = ob; idx = oi; }
        }
        if (lane == 0) s[row] = idx;
    }
    __syncthreads();

    // Each thread's int4 payload is invariant across its grid-stride stores:
    // for i = blk*256 + tid + k*32768, (4i) mod 256 == 4*(tid & 63).
    const int base = lane * 4;
    const int4 v = make_int4(s[base], s[base + 1], s[base + 2], s[base + 3]);
    int4* o4 = (int4*)out;
    for (int i = blockIdx.x * 256 + tid; i < OUT_INT4; i += NBLOCKS * 256) {
        o4[i] = v;
    }
}

extern "C" void kernel_launch(void* const* d_in, const int* in_sizes, int n_in,
                              void* d_out, int out_size, void* d_ws, size_t ws_size,
                              hipStream_t stream) {
    // inputs: 0=input_values (B,L,D) f32, 1=W (Q,D) f32, 2=code_book (C,Q) f32, 3=raw_signal
    const float* code_book = (const float*)d_in[2];
    int* out = (int*)d_out;
    rpq_fused<<<NBLOCKS, 256, 0, stream>>>(code_book, out);
}

// Round 6
// 62.558 us; speedup vs baseline: 1.7548x; 1.7548x over previous
//
#include <hip/hip_runtime.h>

// labels[b,l,c] = argmin_q ( LN(t)[b,l,c] - LN(code_book)[c,q] )
//              = argmax_q LN(code_book)[c,q]        (tn constant along q)
//              = argmax_q code_book[c,q]            (global-scalar LN is monotone)
// => output is a 256-entry per-c label vector broadcast over (B, L).
//
// v6: two-kernel split (v5 profile showed the fused kernel is pure
// latency: 58 us, 52 GB/s, 5% occupancy).
//  K1 rpq_labels: 256 waves, one per row. Lane l holds cols 4l..4l+3 via a
//     single coalesced float4 load (64 lanes x 16B = the whole 1 KB row),
//     in-lane merge, then the 6-step shfl_xor butterfly under the total
//     order (value desc, index asc) — associative+commutative, exact
//     first-index tie-break (HW-verified in v5, absmax=0).
//  K2 rpq_bcast: reads the 1 KB label vector (coalesced int4 per lane),
//     broadcast-stores the 2 MB output with the full chip.
// Cross-kernel visibility of d_ws: dispatch-boundary release/acquire on
// the same stream (standard HSA semantics) — no fence needed in source.

#define C_DIM 256
#define Q_DIM 256
#define OUT_INT4 (4 * 512 * 256 / 4)   // B*L*C / 4 = 131072 int4 stores
#define NB_BCAST 256

__global__ __launch_bounds__(256) void rpq_labels(const float* __restrict__ cb,
                                                  int* __restrict__ lab) {
    const int lane = threadIdx.x & 63;
    const int row  = blockIdx.x * 4 + (threadIdx.x >> 6);  // 64 blocks x 4 waves

    float4 v = *(const float4*)(cb + row * Q_DIM + lane * 4);
    // In-lane merge of 4 candidates, ascending index, strict '>' keeps the
    // earliest index on ties.
    float b  = v.x;
    int  idx = lane * 4;
    if (v.y > b) { b = v.y; idx = lane * 4 + 1; }
    if (v.z > b) { b = v.z; idx = lane * 4 + 2; }
    if (v.w > b) { b = v.w; idx = lane * 4 + 3; }
#pragma unroll
    for (int off = 1; off < 64; off <<= 1) {
        float ob = __shfl_xor(b, off, 64);
        int   oi = __shfl_xor(idx, off, 64);
        if (ob > b || (ob == b && oi < idx)) { b = ob; idx = oi; }
    }
    if (lane == 0) lab[row] = idx;
}

__global__ __launch_bounds__(256) void rpq_bcast(const int* __restrict__ lab,
                                                 int* __restrict__ out) {
    const int tid = threadIdx.x;
    // Thread's int4 payload is invariant across its grid-stride stores:
    // for i = blk*256 + tid + k*65536, (4i) mod 256 == 4*(tid & 63),
    // i.e. int4 index (tid & 63) of the label vector.
    const int4 v = ((const int4*)lab)[tid & 63];
    int4* o4 = (int4*)out;
    for (int i = blockIdx.x * 256 + tid; i < OUT_INT4; i += NB_BCAST * 256) {
        o4[i] = v;
    }
}

extern "C" void kernel_launch(void* const* d_in, const int* in_sizes, int n_in,
                              void* d_out, int out_size, void* d_ws, size_t ws_size,
                              hipStream_t stream) {
    // inputs: 0=input_values (B,L,D) f32, 1=W (Q,D) f32, 2=code_book (C,Q) f32, 3=raw_signal
    const float* code_book = (const float*)d_in[2];
    int* lab = (int*)d_ws;            // 256 ints = 1 KB of workspace
    int* out = (int*)d_out;
    rpq_labels<<<64, 256, 0, stream>>>(code_book, lab);
    rpq_bcast<<<NB_BCAST, 256, 0, stream>>>(lab, out);
}